// Round 3
// baseline (685.339 us; speedup 1.0000x reference)
//
#include <hip/hip_runtime.h>
#include <stdint.h>

// Problem constants
#define NB   256     // batch
#define NT   192     // frames
#define NH   64      // hidden
#define NC   256     // conv channels / scan steps
#define NOUT 28
#define K2   1536    // conv2 reduction = 256ci * 6y (re-keyed as y*256+ci)

typedef __attribute__((ext_vector_type(8))) short short8v;  // 8 bf16 (4 VGPR)
typedef __attribute__((ext_vector_type(4))) float f32x4;    // MFMA acc

// ---------- helpers ----------
__device__ __forceinline__ float lane_bcast(float v, int m) {
    return __int_as_float(__builtin_amdgcn_readlane(__float_as_int(v), m));
}
__device__ __forceinline__ uint16_t f2bf(float f) {          // RNE f32->bf16
    uint32_t u = __float_as_uint(f);
    return (uint16_t)((u + 0x7fffu + ((u >> 16) & 1u)) >> 16);
}
__device__ __forceinline__ uint32_t pk2(float a, float b) {
    return (uint32_t)f2bf(a) | ((uint32_t)f2bf(b) << 16);
}
__device__ __forceinline__ float bf2f(uint16_t u) {
    return __uint_as_float((uint32_t)u << 16);
}
__device__ __forceinline__ float sigmoidf_(float x) { return 1.f / (1.f + __expf(-x)); }
__device__ __forceinline__ float tanhf_(float x) {
    float a = fabsf(x);
    float e = __expf(2.f * a);          // inf for large a is fine: 2/(inf+1)=0
    float r = 1.f - 2.f / (e + 1.f);
    return (x < 0.f) ? -r : r;
}
// raw barrier: LDS-ordering only, does NOT drain vmcnt (keeps global prefetch alive)
__device__ __forceinline__ void wg_barrier() {
    asm volatile("s_waitcnt lgkmcnt(0)\n\ts_barrier" ::: "memory");
}
// async global->LDS, 16 B per lane; LDS dest is wave-uniform base + lane*16
__device__ __forceinline__ void gload_lds16(const uint16_t* g, uint16_t* l) {
    __builtin_amdgcn_global_load_lds(
        (const __attribute__((address_space(1))) uint32_t*)(const void*)g,
        (__attribute__((address_space(3))) uint32_t*)(void*)l, 16, 0, 0);
}
// read one MFMA operand fragment from a [rows][64] bf16 LDS tile, XOR-swizzled
__device__ __forceinline__ short8v frag_ld(const uint16_t* tile, int row, int kchunk) {
    const int kc = kchunk ^ (row & 7);
    return *(const short8v*)(tile + row * 64 + kc * 8);
}

// ---------- K0a: fp32 -> bf16 conversion (n even) ----------
__global__ __launch_bounds__(256) void k_cvt(const float* __restrict__ src,
                                             uint16_t* __restrict__ dst, int n)
{
    int i = blockIdx.x * 256 + threadIdx.x;      // converts 2 elems
    if (2 * i < n) {
        float2 v = *(const float2*)(src + 2 * i);
        ((uint32_t*)dst)[i] = pk2(v.x, v.y);
    }
}

// ---------- K0b: w1 (256,72) fp32 -> w1b_pad (256,104) bf16, k>=72 zero ----------
__global__ __launch_bounds__(256) void k_cvtw1(const float* __restrict__ w1,
                                               uint16_t* __restrict__ dst)
{
    int id = blockIdx.x * 256 + threadIdx.x;     // one u32 pair
    if (id < 256 * 52) {
        int co = id / 52, p = id - co * 52;
        uint32_t v = 0u;
        if (p < 36) {
            float2 q = *(const float2*)(w1 + co * 72 + 2 * p);
            v = pk2(q.x, q.y);
        }
        ((uint32_t*)dst)[id] = v;
    }
}

// ---------- K0c: w2 [co][ci*6+y] fp32 -> w2b [co][y*256+ci] bf16 ----------
__global__ __launch_bounds__(256) void k_cvtw2(const float* __restrict__ w2,
                                               uint16_t* __restrict__ dst)
{
    int id = blockIdx.x * 256 + threadIdx.x;     // one u32 pair
    if (id < 196608) {
        int co  = id / 768;
        int rem = id - co * 768;
        int y   = rem / 128;
        int cp  = rem - y * 128;
        int ci0 = cp * 2;
        float a = w2[(size_t)co * 1536 + ci0 * 6 + y];
        float b = w2[(size_t)co * 1536 + (ci0 + 1) * 6 + y];
        ((uint32_t*)dst)[id] = pk2(a, b);
    }
}

// ---------- K1: conv1 via implicit-GEMM MFMA ----------
// D[co][m=(lt,y)] = sum_{k=(ci,dt,dr,dw)} W[co][k] * P[m][k];  h1 relu'd, k-order y*256+ci
__global__ __launch_bounds__(256) void k_conv1_mfma(const float* __restrict__ x,
                                                    const uint16_t* __restrict__ w1b,
                                                    const float* __restrict__ b1,
                                                    uint16_t* __restrict__ h1)
{
    __shared__ alignas(16) uint16_t Wt[256 * 104];     // 53248 B (DMA, linear)
    __shared__ alignas(16) uint16_t Pt[96 * 100];      // 19200 B (constructed)
    __shared__ alignas(16) float patch[2 * 18 * 64];   //  9216 B [ci][tt][1+f]
    const int tid  = threadIdx.x;
    const int w    = tid >> 6;
    const int lane = tid & 63;
    const int tblk = blockIdx.x;                       // 0..11
    const int b    = blockIdx.y;                       // 0..255
    const int t0   = tblk * 16;

    // 1) issue W DMA: 3328 16B-chunks, 13 per lane
    #pragma unroll
    for (int i = 0; i < 13; i++) {
        const int cbase = i * 256 + w * 64;
        gload_lds16(w1b + (size_t)(cbase + lane) * 8, &Wt[cbase * 8]);
    }

    // 2) stage fp32 patch (frames t0-1 .. t0+16), zero-pad t boundary
    for (int idx = tid; idx < 2 * 18 * 63; idx += 256) {
        int ci  = idx / 1134;
        int rem = idx - ci * 1134;
        int tt  = rem / 63;
        int f   = rem - tt * 63;
        int gf  = t0 - 1 + tt;
        float v = 0.f;
        if (gf >= 0 && gf < NT) v = x[(size_t)b * 24192 + ci * 12096 + gf * 63 + f];
        patch[ci * 1152 + tt * 64 + 1 + f] = v;
    }
    __syncthreads();   // patch ready (also drains W DMA; fine, one-shot kernel)

    // 3) construct P[m][k]: m=lt*6+y, k=cd*12 + (dr*3+dw), cd=(ci,dt); rows stride 100
    for (int l = 0; l < 3; l++) {
        int idx = tid + l * 256;
        if (idx < 576) {
            int m  = idx / 6;
            int cd = idx - m * 6;
            int ci = cd / 3, dt = cd - ci * 3;
            int lt = m / 6,  y  = m - lt * 6;
            const float* pb = &patch[ci * 1152 + (lt + dt) * 64];
            uint2* dst = (uint2*)(Pt + m * 100 + cd * 12);   // 24B, 8B-aligned
            if (y == 0) {   // rows -3..0: dr<3 zero, dr=3 -> pb[1..3]
                dst[0] = (uint2){0u, 0u};
                dst[1] = (uint2){0u, (uint32_t)f2bf(pb[1]) << 16};
                dst[2] = (uint2){pk2(pb[2], pb[3]), 0u};
                // note: last pair is (pb[2],pb[3]) then nothing -> careful below
            } else {
                const float4* q = (const float4*)(pb + 12 * y - 8);
                float4 q0 = q[0], q1 = q[1], q2 = q[2];
                dst[0] = (uint2){pk2(q0.x, q0.y), pk2(q0.z, q0.w)};
                dst[1] = (uint2){pk2(q1.x, q1.y), pk2(q1.z, q1.w)};
                dst[2] = (uint2){pk2(q2.x, q2.y), pk2(q2.z, q2.w)};
            }
        }
    }
    // fix y==0 layout: 12 values are [0]*9, pb1, pb2, pb3 -> pairs:
    // (0,0)(0,0)(0,0)(0,0)(0,pb1)(pb2,pb3). Rewrite cleanly (cheap, correct):
    for (int l = 0; l < 3; l++) {
        int idx = tid + l * 256;
        if (idx < 576) {
            int m  = idx / 6;
            int cd = idx - m * 6;
            int lt = m / 6, y = m - lt * 6;
            if (y == 0) {
                int ci = cd / 3, dt = cd - ci * 3;
                const float* pb = &patch[ci * 1152 + (lt + dt) * 64];
                uint2* dst = (uint2*)(Pt + m * 100 + cd * 12);
                dst[0] = (uint2){0u, 0u};
                dst[1] = (uint2){0u, 0u};
                dst[2] = (uint2){(uint32_t)f2bf(pb[1]) << 16, pk2(pb[2], pb[3])};
            }
        }
    }
    // zero P k-pad 72..95 (both operands' pad zero => safe vs stale LDS)
    {
        int idx = tid;
        if (idx < 192) {
            int m = idx >> 1, half = idx & 1;
            uint2* dst = (uint2*)(Pt + m * 100 + 72 + half * 12);
            dst[0] = (uint2){0u, 0u};
            dst[1] = (uint2){0u, 0u};
            dst[2] = (uint2){0u, 0u};
        }
    }
    wg_barrier();      // P writes visible (W already drained)

    // 4) GEMM: wave w -> co tiles w*4..w*4+3 (64 co) x all 6 m-tiles, 3 K-steps
    f32x4 acc[4][6];
    #pragma unroll
    for (int i = 0; i < 4; i++)
        #pragma unroll
        for (int j = 0; j < 6; j++) acc[i][j] = (f32x4){0.f, 0.f, 0.f, 0.f};

    #pragma unroll
    for (int kstep = 0; kstep < 3; kstep++) {
        const int kch = kstep * 4 + (lane >> 4);       // chunk 0..11
        short8v wf[4], pf[6];
        #pragma unroll
        for (int at = 0; at < 4; at++)
            wf[at] = *(const short8v*)(Wt + ((w * 4 + at) * 16 + (lane & 15)) * 104 + kch * 8);
        #pragma unroll
        for (int mt = 0; mt < 6; mt++)
            pf[mt] = *(const short8v*)(Pt + (mt * 16 + (lane & 15)) * 100 + kch * 8);
        #pragma unroll
        for (int at = 0; at < 4; at++)
            #pragma unroll
            for (int mt = 0; mt < 6; mt++)
                acc[at][mt] = __builtin_amdgcn_mfma_f32_16x16x32_bf16(
                    wf[at], pf[mt], acc[at][mt], 0, 0, 0);
    }

    // 5) epilogue: D layout col(lane&15)=m, row((lane>>4)*4+reg)=co; relu; h1 k=y*256+ci
    #pragma unroll
    for (int mt = 0; mt < 6; mt++) {
        const int m  = mt * 16 + (lane & 15);
        const int lt = m / 6, y = m - lt * 6;
        uint16_t* rowp = h1 + (size_t)(b * NT + t0 + lt) * K2 + y * 256;
        #pragma unroll
        for (int at = 0; at < 4; at++) {
            const int co0 = (w * 4 + at) * 16 + (lane >> 4) * 4;
            float4 b4 = *(const float4*)&b1[co0];
            f32x4 v = acc[at][mt];
            float r0 = fmaxf(v[0] + b4.x, 0.f), r1 = fmaxf(v[1] + b4.y, 0.f);
            float r2 = fmaxf(v[2] + b4.z, 0.f), r3 = fmaxf(v[3] + b4.w, 0.f);
            *(uint2*)(rowp + co0) = (uint2){pk2(r0, r1), pk2(r2, r3)};
        }
    }
}

// ---------- K2: unified bf16 MFMA GEMM ----------
// C[arow][bcol] = sum_k A[arow][k] * B[bcol][k]  (both operands [entity][k] bf16)
// Block tile: 64 A-rows x 256 B-rows, K-step 64, double-buffered LDS via
// global_load_lds(16B), XOR-swizzled chunks (kc ^= row&7) -> conflict-free b128 reads.
// MODE 0 (conv2): A=h1[bt][1536], B=w2b[co][1536]; out=featsb[(b*256+co)][t] bf16 +b2[co]
// MODE 1 (g1pre): A=w_ih1b[g][256], B=featsb[btj][192]; out=g1b[btj][g] bf16 +b_ih1[g]
template<int MODE>
__global__ __launch_bounds__(256) void k_gemm(const uint16_t* __restrict__ A,
                                              const uint16_t* __restrict__ B,
                                              const float* __restrict__ bias,
                                              uint16_t* __restrict__ out,
                                              int kSteps, int lda, int ldb)
{
    __shared__ alignas(16) uint16_t As[2][64 * 64];     // 16 KB
    __shared__ alignas(16) uint16_t Bs[2][256 * 64];    // 64 KB
    const int tid  = threadIdx.x;
    const int w    = tid >> 6;
    const int lane = tid & 63;
    const int a0   = blockIdx.x * 64;
    const int b0   = blockIdx.y * 256;

    f32x4 acc[4][4];
    #pragma unroll
    for (int i = 0; i < 4; i++)
        #pragma unroll
        for (int j = 0; j < 4; j++) acc[i][j] = (f32x4){0.f, 0.f, 0.f, 0.f};

    auto stage = [&](int buf, int k0) {
        #pragma unroll
        for (int i = 0; i < 2; i++) {                    // A: 512 chunks, 2 instr/wave
            int c   = w * 128 + i * 64 + lane;
            int row = c >> 3;
            int kc  = (c & 7) ^ (row & 7);               // inverse swizzle on SOURCE
            gload_lds16(A + (size_t)(a0 + row) * lda + k0 + kc * 8,
                        &As[buf][(w * 128 + i * 64) * 8]);
        }
        #pragma unroll
        for (int i = 0; i < 8; i++) {                    // B: 2048 chunks, 8 instr/wave
            int c   = w * 512 + i * 64 + lane;
            int row = c >> 3;
            int kc  = (c & 7) ^ (row & 7);
            gload_lds16(B + (size_t)(b0 + row) * ldb + k0 + kc * 8,
                        &Bs[buf][(w * 512 + i * 64) * 8]);
        }
    };

    stage(0, 0);
    for (int t = 0; t < kSteps; ++t) {
        const int cur = t & 1;
        if (t + 1 < kSteps) {
            stage(cur ^ 1, (t + 1) * 64);
            asm volatile("s_waitcnt vmcnt(10)" ::: "memory");  // cur's 10 done, next 10 in flight
        } else {
            asm volatile("s_waitcnt vmcnt(0)" ::: "memory");
        }
        __builtin_amdgcn_sched_barrier(0);
        __builtin_amdgcn_s_barrier();
        __builtin_amdgcn_sched_barrier(0);
        #pragma unroll
        for (int ks = 0; ks < 2; ++ks) {
            short8v af[4], bf[4];
            const int kch = ks * 4 + (lane >> 4);
            #pragma unroll
            for (int rt = 0; rt < 4; rt++)
                af[rt] = frag_ld(As[cur], rt * 16 + (lane & 15), kch);
            #pragma unroll
            for (int ct = 0; ct < 4; ct++)
                bf[ct] = frag_ld(Bs[cur], w * 64 + ct * 16 + (lane & 15), kch);
            #pragma unroll
            for (int rt = 0; rt < 4; rt++)
                #pragma unroll
                for (int ct = 0; ct < 4; ct++)
                    acc[rt][ct] = __builtin_amdgcn_mfma_f32_16x16x32_bf16(
                        af[rt], bf[ct], acc[rt][ct], 0, 0, 0);
        }
        asm volatile("s_waitcnt lgkmcnt(0)" ::: "memory");     // ds_reads done before reuse
        __builtin_amdgcn_sched_barrier(0);
        __builtin_amdgcn_s_barrier();
        __builtin_amdgcn_sched_barrier(0);
    }

    // epilogue: C/D layout col=lane&15, row=(lane>>4)*4+reg  [m89-verified]
    const int rsub = (lane >> 4) * 4;
    #pragma unroll
    for (int rt = 0; rt < 4; rt++) {
        if constexpr (MODE == 0) {
            const int bt = a0 + rt * 16 + rsub;          // 4 consecutive bt (regs 0..3)
            const int bb = bt / NT, tt = bt - bb * NT;   // bt%4==0 -> never straddles b
            #pragma unroll
            for (int ct = 0; ct < 4; ct++) {
                const int co = w * 64 + ct * 16 + (lane & 15);
                const float bv = bias[co];
                f32x4 v = acc[rt][ct];
                uint2 st = { pk2(v[0] + bv, v[1] + bv), pk2(v[2] + bv, v[3] + bv) };
                *(uint2*)&out[(size_t)(bb * 256 + co) * NT + tt] = st;
            }
        } else {
            const int g = a0 + rt * 16 + rsub;           // 4 consecutive gates
            const float4 b4 = *(const float4*)&bias[g];
            #pragma unroll
            for (int ct = 0; ct < 4; ct++) {
                const int btj = b0 + w * 64 + ct * 16 + (lane & 15);
                f32x4 v = acc[rt][ct];
                uint2 st = { pk2(v[0] + b4.x, v[1] + b4.y), pk2(v[2] + b4.z, v[3] + b4.w) };
                *(uint2*)&out[(size_t)btj * NT + g] = st;
            }
        }
    }
}

// ---------- K4: fused GRU1+GRU2 scan (one workgroup per batch row) ----------
// 384 threads: t<192 -> gx-column t; t>=192 -> gh-column t-192. h wave-replicated.
__global__ __launch_bounds__(384) void k_scan(const uint16_t* __restrict__ g1b,
                                              const float* __restrict__ w_ih1,
                                              const float* __restrict__ w_hh1,
                                              const float* __restrict__ b_hh1,
                                              const float* __restrict__ w_ih2,
                                              const float* __restrict__ w_hh2,
                                              const float* __restrict__ b_ih2,
                                              const float* __restrict__ b_hh2,
                                              float* __restrict__ outs2)
{
    __shared__ float u0[384];
    __shared__ float u1[384];
    const int b    = blockIdx.x;
    const int t    = threadIdx.x;
    const int lane = t & 63;

    float wA[64], wB[64], bA, bB;
    if (t < 192) {
        const float4* p = (const float4*)(w_ih1 + t * 256 + 192);  // h-part of w_ih1
        const float4* q = (const float4*)(w_ih2 + t * 64);
        #pragma unroll
        for (int i = 0; i < 16; i++) {
            float4 a = p[i]; wA[4*i]=a.x; wA[4*i+1]=a.y; wA[4*i+2]=a.z; wA[4*i+3]=a.w;
            float4 c = q[i]; wB[4*i]=c.x; wB[4*i+1]=c.y; wB[4*i+2]=c.z; wB[4*i+3]=c.w;
        }
        bA = 0.f; bB = b_ih2[t];
    } else {
        const float4* p = (const float4*)(w_hh1 + (t - 192) * 64);
        const float4* q = (const float4*)(w_hh2 + (t - 192) * 64);
        #pragma unroll
        for (int i = 0; i < 16; i++) {
            float4 a = p[i]; wA[4*i]=a.x; wA[4*i+1]=a.y; wA[4*i+2]=a.z; wA[4*i+3]=a.w;
            float4 c = q[i]; wB[4*i]=c.x; wB[4*i+1]=c.y; wB[4*i+2]=c.z; wB[4*i+3]=c.w;
        }
        bA = b_hh1[t - 192]; bB = b_hh2[t - 192];
    }

    float h1v = 0.f, h2v = 0.f;
    float pre = (t < 192) ? bf2f(g1b[(size_t)(b * 256) * NT + t]) : 0.f;

    for (int j = 0; j < 256; ++j) {
        // prefetch next step's gx-pre (survives raw barriers; no vmcnt drain)
        const int jn = (j + 1 < 256) ? j + 1 : 255;
        uint16_t pn = (t < 192) ? g1b[(size_t)(b * 256 + jn) * NT + t] : (uint16_t)0;

        // phase A: GRU1 hidden-dependent matvec (4-way split dep chain)
        float d0 = 0.f, d1 = 0.f, d2 = 0.f, d3 = 0.f;
        #pragma unroll
        for (int m = 0; m < 64; m += 4) {
            d0 = fmaf(lane_bcast(h1v, m    ), wA[m    ], d0);
            d1 = fmaf(lane_bcast(h1v, m + 1), wA[m + 1], d1);
            d2 = fmaf(lane_bcast(h1v, m + 2), wA[m + 2], d2);
            d3 = fmaf(lane_bcast(h1v, m + 3), wA[m + 3], d3);
        }
        float d = (d0 + d1) + (d2 + d3);
        u0[t] = (t < 192) ? (pre + d) : (d + bA);
        wg_barrier();
        {
            float gxr = u0[lane],       gxz = u0[64 + lane],  gxn = u0[128 + lane];
            float ghr = u0[192 + lane], ghz = u0[256 + lane], ghn = u0[320 + lane];
            float r = sigmoidf_(gxr + ghr);
            float z = sigmoidf_(gxz + ghz);
            float n = tanhf_(gxn + r * ghn);
            h1v = (1.f - z) * n + z * h1v;
        }
        // phase B: GRU2 (input = new h1)
        const float src = (t < 192) ? h1v : h2v;
        float e0 = bB, e1 = 0.f, e2 = 0.f, e3 = 0.f;
        #pragma unroll
        for (int m = 0; m < 64; m += 4) {
            e0 = fmaf(lane_bcast(src, m    ), wB[m    ], e0);
            e1 = fmaf(lane_bcast(src, m + 1), wB[m + 1], e1);
            e2 = fmaf(lane_bcast(src, m + 2), wB[m + 2], e2);
            e3 = fmaf(lane_bcast(src, m + 3), wB[m + 3], e3);
        }
        u1[t] = (e0 + e1) + (e2 + e3);
        wg_barrier();
        {
            float gxr = u1[lane],       gxz = u1[64 + lane],  gxn = u1[128 + lane];
            float ghr = u1[192 + lane], ghz = u1[256 + lane], ghn = u1[320 + lane];
            float r = sigmoidf_(gxr + ghr);
            float z = sigmoidf_(gxz + ghz);
            float n = tanhf_(gxn + r * ghn);
            h2v = (1.f - z) * n + z * h2v;
        }
        if (t < 64) outs2[(size_t)(b * 256 + j) * 64 + t] = h2v;
        pre = bf2f(pn);
    }
}

// ---------- K5: FC head  out = relu(o2 @ fc1_w.T + b1) @ fc2_w.T + b2 ----------
__global__ __launch_bounds__(256) void k_fc(const float* __restrict__ o2,
                                            const float* __restrict__ fc1_w,
                                            const float* __restrict__ fc1_b,
                                            const float* __restrict__ fc2_w,
                                            const float* __restrict__ fc2_b,
                                            float* __restrict__ out)
{
    const int lane = threadIdx.x & 63;
    const int wid  = blockIdx.x * 4 + (threadIdx.x >> 6);   // 0..2047

    float w1[64], w2[64];
    {
        const float4* p = (const float4*)(fc1_w + lane * 64);
        #pragma unroll
        for (int i = 0; i < 16; i++) {
            float4 a = p[i]; w1[4*i]=a.x; w1[4*i+1]=a.y; w1[4*i+2]=a.z; w1[4*i+3]=a.w;
        }
    }
    const float b1v = fc1_b[lane];
    float b2v = 0.f;
    if (lane < NOUT) {
        const float4* p = (const float4*)(fc2_w + lane * 64);
        #pragma unroll
        for (int i = 0; i < 16; i++) {
            float4 a = p[i]; w2[4*i]=a.x; w2[4*i+1]=a.y; w2[4*i+2]=a.z; w2[4*i+3]=a.w;
        }
        b2v = fc2_b[lane];
    } else {
        #pragma unroll
        for (int i = 0; i < 64; i++) w2[i] = 0.f;
    }

    for (int r = wid; r < NB * NC; r += 2048) {
        float v = o2[(size_t)r * 64 + lane];
        float y = b1v;
        #pragma unroll
        for (int m = 0; m < 64; m++) y = fmaf(lane_bcast(v, m), w1[m], y);
        y = fmaxf(y, 0.f);
        float o = b2v;
        #pragma unroll
        for (int m = 0; m < 64; m++) o = fmaf(lane_bcast(y, m), w2[m], o);
        if (lane < NOUT) out[(size_t)r * NOUT + lane] = o;
    }
}

// ---------- launch ----------
extern "C" void kernel_launch(void* const* d_in, const int* in_sizes, int n_in,
                              void* d_out, int out_size, void* d_ws, size_t ws_size,
                              hipStream_t stream)
{
    (void)in_sizes; (void)n_in; (void)out_size;
    const float* x       = (const float*)d_in[0];
    const float* conv1_w = (const float*)d_in[1];
    const float* conv1_b = (const float*)d_in[2];
    const float* conv2_w = (const float*)d_in[3];
    const float* conv2_b = (const float*)d_in[4];
    const float* w_ih1   = (const float*)d_in[5];
    const float* w_hh1   = (const float*)d_in[6];
    const float* b_ih1   = (const float*)d_in[7];
    const float* b_hh1   = (const float*)d_in[8];
    const float* w_ih2   = (const float*)d_in[9];
    const float* w_hh2   = (const float*)d_in[10];
    const float* b_ih2   = (const float*)d_in[11];
    const float* b_hh2   = (const float*)d_in[12];
    const float* fc1_w   = (const float*)d_in[13];
    const float* fc1_b   = (const float*)d_in[14];
    const float* fc2_w   = (const float*)d_in[15];
    const float* fc2_b   = (const float*)d_in[16];
    float* out = (float*)d_out;

    // workspace layout (total 219,041,792 B ~ 209 MiB)
    if (ws_size < 219041792ull) return;  // fail "incorrect", not a fault
    char* ws = (char*)d_ws;
    uint16_t* h1      = (uint16_t*)(ws);               // 150,994,944 B  bf16 [bt][y*256+ci]
    uint16_t* featsb  = (uint16_t*)(ws + 150994944);   //  25,165,824 B  bf16 [b*256+co][192]
    uint16_t* g1b     = (uint16_t*)(ws + 176160768);   //  25,165,824 B  bf16 [b*256+j][192]
    float*    o2      = (float*)   (ws + 201326592);   //  16,777,216 B  f32  [b*256+j][64]
    uint16_t* w2b     = (uint16_t*)(ws + 218103808);   //     786,432 B  bf16 [co][y*256+ci]
    uint16_t* w_ih1b  = (uint16_t*)(ws + 218890240);   //      98,304 B  bf16 [g][256]
    uint16_t* w1b     = (uint16_t*)(ws + 218988544);   //      53,248 B  bf16 [co][104] k-pad

    k_cvtw1<<<dim3(52),  256, 0, stream>>>(conv1_w, w1b);
    k_cvtw2<<<dim3(768), 256, 0, stream>>>(conv2_w, w2b);
    k_cvt  <<<dim3(96),  256, 0, stream>>>(w_ih1, w_ih1b, 49152);
    k_conv1_mfma<<<dim3(12, 256), 256, 0, stream>>>(x, w1b, conv1_b, h1);
    // conv2: M=49152 bt, N=256 co (one B-tile), K=1536 (24 steps)
    k_gemm<0><<<dim3(768, 1), 256, 0, stream>>>(h1, w2b, conv2_b, featsb, 24, K2, K2);
    // g1pre: M=192 g, N=65536 btj, K=192 (3 steps)
    k_gemm<1><<<dim3(3, 256), 256, 0, stream>>>(w_ih1b, featsb, b_ih1, g1b, 3, 256, NT);
    k_scan<<<dim3(256), 384, 0, stream>>>(g1b, w_ih1, w_hh1, b_hh1,
                                          w_ih2, w_hh2, b_ih2, b_hh2, o2);
    k_fc<<<dim3(512), 256, 0, stream>>>(o2, fc1_w, fc1_b, fc2_w, fc2_b, out);
}